// Round 9
// baseline (255.542 us; speedup 1.0000x reference)
//
#include <hip/hip_runtime.h>
#include <hip/hip_bf16.h>

#define Bn 16
#define Tn 64
#define Cn 512
#define LDA  520    // bf16 row stride in shorts (pre A tile)
#define LDA8 528    // fp8 row stride in bytes (fused A tile)

#define LOG2E 1.4426950408889634f
#define LN2   0.6931471805599453f
#define ASC 16.0f          // A (relu h) scale, folded into xe / Wt
#define WSC 256.0f         // W_imp scale (lifts out of e4m3 subnormals)
#define ZSC (1.0f/4096.0f) // 1/(ASC*WSC) unscale
#define NZL (-(LOG2E)*(ZSC)) // folded -log2e/4096 for sigmoid arg
#define SC1 0x7F7F7F7FU    // E8M0 unit scales (127 -> 2^0)

typedef short s8v __attribute__((ext_vector_type(8)));          // 8 bf16 frag
typedef float f4v __attribute__((ext_vector_type(4)));          // MFMA acc
typedef int   i8v __attribute__((ext_vector_type(8)));          // 32B fp8 frag (K=128)

__device__ __forceinline__ unsigned int pk2bf(float a, float b){
  __hip_bfloat162 t = __float22bfloat162_rn(make_float2(a, b));
  union { __hip_bfloat162 h; unsigned int u; } c; c.h = t; return c.u;
}
__device__ __forceinline__ float bits2f(unsigned int u){
  union { unsigned int u; float f; } c; c.u = u; return c.f;
}
__device__ __forceinline__ s8v pack_bf8(const float* v){
  union { uint4 u; s8v s; } c;
  c.u.x = pk2bf(v[0], v[1]); c.u.y = pk2bf(v[2], v[3]);
  c.u.z = pk2bf(v[4], v[5]); c.u.w = pk2bf(v[6], v[7]);
  return c.s;
}
union U8 { uint4 q[2]; i8v v; };

// ---------------------------------------------------------------------------
// pre: 192 blocks x 512 thr (single CU generation).
//  [0,32):   R table log1p(max(+/-(ts_i-ts_j),0)) -> R
//  [32,64):  Wi f32 *256 -> fp8 e4m3 K=128 frag planes (round-7 layout)
//  [64,192): GEMM blocks (b, mat, half): 8 waves, wave = 1 n-tile t=half*8+w.
//     mat=0: values=x@Wp+bp -> vfrag bf16 *log2e (fused C-frag order)
//     mat=1: xe=(x@Wx+bx+bt)*ASC (f32 row-major)
// ---------------------------------------------------------------------------
__global__ __launch_bounds__(512)
void pre(const float* __restrict__ x, const float* __restrict__ ts,
         const float* __restrict__ Wp, const float* __restrict__ bp,
         const float* __restrict__ Wx, const float* __restrict__ bx,
         const float* __restrict__ bt, const float* __restrict__ Wi,
         float* __restrict__ xe, unsigned short* __restrict__ vfrag,
         unsigned char* __restrict__ Wsw8, float* __restrict__ R){
  __shared__ unsigned short lA[Tn * LDA];
  const int blk = blockIdx.x;
  const int tid = threadIdx.x;
  if(blk < 32){
    int gid2 = blk * 512 + tid;                      // 16384 threads, 4 pairs each
    float r[8];
#pragma unroll
    for(int q = 0; q < 4; ++q){
      int p = gid2 * 4 + q;
      int b = p >> 12, i = (p >> 6) & 63, j = p & 63;
      float d = ts[b * Tn + i] - ts[b * Tn + j];
      r[2*q]   = __logf(1.f + fmaxf(d, 0.f));
      r[2*q+1] = __logf(1.f + fmaxf(-d, 0.f));
    }
    float4* Rf4 = reinterpret_cast<float4*>(R);
    Rf4[gid2 * 2    ] = make_float4(r[0], r[1], r[2], r[3]);
    Rf4[gid2 * 2 + 1] = make_float4(r[4], r[5], r[6], r[7]);
    return;
  }
  if(blk < 64){
    int rem = (blk - 32) * 512 + tid;                // 16384 threads, 16B each
    int p    = rem & 1;
    int lane = (rem >> 1) & 63;
    int t    = (rem >> 7) & 31;
    int s128 = rem >> 12;
    int quad = lane >> 4, ln = lane & 15;
    int k0 = s128 * 128 + quad * 32 + p * 16;
    int n  = t * 16 + ln;
    float v[16];
#pragma unroll
    for(int j = 0; j < 16; ++j) v[j] = Wi[(k0 + j) * Cn + n] * WSC;
    unsigned int d[4];
#pragma unroll
    for(int g = 0; g < 4; ++g){
      int dd = __builtin_amdgcn_cvt_pk_fp8_f32(v[4*g],   v[4*g+1], 0, false);
      dd     = __builtin_amdgcn_cvt_pk_fp8_f32(v[4*g+2], v[4*g+3], dd, true);
      d[g] = (unsigned int)dd;
    }
    uint4 o; o.x = d[0]; o.y = d[1]; o.z = d[2]; o.w = d[3];
    *reinterpret_cast<uint4*>(Wsw8 + (size_t)(s128 * 32 + t) * 2048 + p * 1024 + lane * 16) = o;
    return;
  }
  // ---- GEMM blocks ----
  const int idx = blk - 64;
  const int b = idx >> 3, mat = (idx >> 2) & 1, half = idx & 3;
  const int lane = tid & 63, w = tid >> 6, quad = lane >> 4, ln = lane & 15;
  const int t = half * 8 + w;                        // n-tile 0..31
  const float* Wg = mat ? Wx : Wp;
  const float* wb = Wg + (size_t)(quad * 8) * Cn + t * 16 + ln;

  const int c0 = (tid & 127) * 4, jb = tid >> 7;     // jb in {0..3}
#pragma unroll
  for(int it = 0; it < 16; ++it){
    int j = jb + it * 4;
    f4v xv = *reinterpret_cast<const f4v*>(x + ((b * Tn + j) * Cn + c0));
    uint2 uu; uu.x = pk2bf(xv[0], xv[1]); uu.y = pk2bf(xv[2], xv[3]);
    *reinterpret_cast<uint2*>(&lA[j * LDA + c0]) = uu;
  }
  float wv[8];
#pragma unroll
  for(int j = 0; j < 8; ++j) wv[j] = wb[j * Cn];
  __syncthreads();

  s8v a[4], an[4];
#pragma unroll
  for(int mt = 0; mt < 4; ++mt)
    a[mt] = *reinterpret_cast<const s8v*>(&lA[(mt * 16 + ln) * LDA + quad * 8]);
  f4v acc[4];
#pragma unroll
  for(int mt = 0; mt < 4; ++mt){ acc[mt][0]=0.f; acc[mt][1]=0.f; acc[mt][2]=0.f; acc[mt][3]=0.f; }
  s8v bcur = pack_bf8(wv);

#pragma unroll 2
  for(int s = 0; s < 16; ++s){
    int sn = (s + 1) & 15;
    float wn[8];
#pragma unroll
    for(int j = 0; j < 8; ++j) wn[j] = wb[(size_t)sn * 32 * Cn + j * Cn];
#pragma unroll
    for(int mt = 0; mt < 4; ++mt)
      an[mt] = *reinterpret_cast<const s8v*>(&lA[(mt * 16 + ln) * LDA + sn * 32 + quad * 8]);
#pragma unroll
    for(int mt = 0; mt < 4; ++mt)
      acc[mt] = __builtin_amdgcn_mfma_f32_16x16x32_bf16(a[mt], bcur, acc[mt], 0, 0, 0);
#pragma unroll
    for(int mt = 0; mt < 4; ++mt) a[mt] = an[mt];
    bcur = pack_bf8(wn);
  }

  const int c = t * 16 + ln;
  const int oct = t >> 2, w2 = t & 3;
  if(mat == 0){
    float bb = bp[c];
    const int eb_h = w2 & 1;
#pragma unroll
    for(int mt = 0; mt < 4; ++mt){
      float v0 = (acc[mt][0] + bb) * LOG2E;
      float v1 = (acc[mt][1] + bb) * LOG2E;
      float v2 = (acc[mt][2] + bb) * LOG2E;
      float v3 = (acc[mt][3] + bb) * LOG2E;
      uint2 o; o.x = pk2bf(v0, v1); o.y = pk2bf(v2, v3);
      int eb = mt * 2 + (w2 >> 1);
      *reinterpret_cast<uint2*>(vfrag + ((size_t)((b * 8 + oct) * 8 + eb) * 64 + lane) * 8 + eb_h * 4) = o;
    }
  } else {
    float bb = bx[c] + bt[c];
#pragma unroll
    for(int mt = 0; mt < 4; ++mt)
#pragma unroll
      for(int r = 0; r < 4; ++r){
        int j = mt * 16 + quad * 4 + r;
        xe[(b * Tn + j) * Cn + c] = (acc[mt][r] + bb) * ASC;
      }
  }
}

// ---------------------------------------------------------------------------
// fused: split-phase. Build rows 0-31 -> barrier -> section A: K(mt0/1) with
// rows-32-63 build interleaved (VALU in MFMA shadow) -> barrier -> section B:
// K(mt2/3) with mt0/1 sigmoid+rowsum interleaved -> mt2/3 sigmoid -> se pass.
// B loaded in 16-reg halves; arch-VGPR set kept <= ~56 (acc = 64 AGPRs).
// ---------------------------------------------------------------------------
__global__ __launch_bounds__(512, 4)
void fused(const float* __restrict__ x, const float* __restrict__ am,
           const float* __restrict__ Wt, const float* __restrict__ bimp,
           const unsigned char* __restrict__ Wsw8, const float* __restrict__ R,
           const float* __restrict__ xe, const unsigned short* __restrict__ vfrag,
           float* __restrict__ out0, float* __restrict__ out1){
  __shared__ unsigned char lA8[Tn * LDA8];
  __shared__ float msk[Tn], rsum[Tn];
  const int b = blockIdx.x >> 6, i = blockIdx.x & 63;
  const int tid = threadIdx.x;
  const int lane = tid & 63, w = tid >> 6, quad = lane >> 4, ln = lane & 15;
  const int st = blockIdx.x & 3;                     // K start phase 0..3
  const int bi = b * Tn + i;
  const float2* R2 = reinterpret_cast<const float2*>(R) + (size_t)bi * Tn;

  if(tid < Tn){ msk[tid] = am[b * Tn + tid]; rsum[tid] = 0.f; }

  const int c0 = (tid & 127) * 4, jb = tid >> 7;
  f4v wt0 = *reinterpret_cast<const f4v*>(Wt + c0);
  f4v wt1 = *reinterpret_cast<const f4v*>(Wt + Cn + c0);
  wt0[0]*=ASC; wt0[1]*=ASC; wt0[2]*=ASC; wt0[3]*=ASC;   // xe already x16
  wt1[0]*=ASC; wt1[1]*=ASC; wt1[2]*=ASC; wt1[3]*=ASC;

  // ---- build rows 0..31 (its 0..7) ----
  f4v xv[8]; float2 rv[8];
#pragma unroll
  for(int it = 0; it < 8; ++it){
    int j = jb + it * 4;
    xv[it] = *reinterpret_cast<const f4v*>(xe + ((size_t)(b * Tn + j) * Cn + c0));
    rv[it] = R2[j];
  }
#pragma unroll
  for(int it = 0; it < 8; ++it){
    int j = jb + it * 4;
    float r0 = rv[it].x, r1 = rv[it].y;
    float h0 = fmaxf(fmaf(r1, wt1[0], fmaf(r0, wt0[0], xv[it][0])), 0.f);
    float h1 = fmaxf(fmaf(r1, wt1[1], fmaf(r0, wt0[1], xv[it][1])), 0.f);
    float h2 = fmaxf(fmaf(r1, wt1[2], fmaf(r0, wt0[2], xv[it][2])), 0.f);
    float h3 = fmaxf(fmaf(r1, wt1[3], fmaf(r0, wt0[3], xv[it][3])), 0.f);
    int d = __builtin_amdgcn_cvt_pk_fp8_f32(h0, h1, 0, false);
    d     = __builtin_amdgcn_cvt_pk_fp8_f32(h2, h3, d, true);
    *reinterpret_cast<int*>(lA8 + j * LDA8 + c0) = d;
  }
  __syncthreads();

  f4v acc[4][4];
#pragma unroll
  for(int mt = 0; mt < 4; ++mt)
#pragma unroll
    for(int nt = 0; nt < 4; ++nt){
      acc[mt][nt][0]=0.f; acc[mt][nt][1]=0.f; acc[mt][nt][2]=0.f; acc[mt][nt][3]=0.f;
    }

  // ---- section A: K for mt0/1 + build rows 32..63 interleaved ----
#pragma unroll 1
  for(int sI = 0; sI < 4; ++sI){
    const int s128 = (st + sI) & 3;
    const int jA = jb + 32 + sI * 8, jB = jA + 4;    // its 8+2sI, 9+2sI
    f4v xA = *reinterpret_cast<const f4v*>(xe + ((size_t)(b * Tn + jA) * Cn + c0));
    f4v xB = *reinterpret_cast<const f4v*>(xe + ((size_t)(b * Tn + jB) * Cn + c0));
    float2 rA = R2[jA], rB = R2[jB];
    const unsigned char* Bb = Wsw8 + (size_t)(s128 * 32 + w * 4) * 2048 + (size_t)lane * 16;
    U8 a0, a1;
    const unsigned char* ap0 = lA8 + ln * LDA8 + s128 * 128 + quad * 32;
    const unsigned char* ap1 = ap0 + 16 * LDA8;
    a0.q[0] = *reinterpret_cast<const uint4*>(ap0);
    a0.q[1] = *reinterpret_cast<const uint4*>(ap0 + 16);
    a1.q[0] = *reinterpret_cast<const uint4*>(ap1);
    a1.q[1] = *reinterpret_cast<const uint4*>(ap1 + 16);
    {
      U8 u0, u1;
      u0.q[0] = *reinterpret_cast<const uint4*>(Bb);
      u0.q[1] = *reinterpret_cast<const uint4*>(Bb + 1024);
      u1.q[0] = *reinterpret_cast<const uint4*>(Bb + 2048);
      u1.q[1] = *reinterpret_cast<const uint4*>(Bb + 3072);
      acc[0][0] = __builtin_amdgcn_mfma_scale_f32_16x16x128_f8f6f4(a0.v, u0.v, acc[0][0], 0, 0, 0, SC1, 0, SC1);
      acc[0][1] = __builtin_amdgcn_mfma_scale_f32_16x16x128_f8f6f4(a0.v, u1.v, acc[0][1], 0, 0, 0, SC1, 0, SC1);
      acc[1][0] = __builtin_amdgcn_mfma_scale_f32_16x16x128_f8f6f4(a1.v, u0.v, acc[1][0], 0, 0, 0, SC1, 0, SC1);
      acc[1][1] = __builtin_amdgcn_mfma_scale_f32_16x16x128_f8f6f4(a1.v, u1.v, acc[1][1], 0, 0, 0, SC1, 0, SC1);
    }
    {
      U8 u2, u3;
      u2.q[0] = *reinterpret_cast<const uint4*>(Bb + 4096);
      u2.q[1] = *reinterpret_cast<const uint4*>(Bb + 5120);
      u3.q[0] = *reinterpret_cast<const uint4*>(Bb + 6144);
      u3.q[1] = *reinterpret_cast<const uint4*>(Bb + 7168);
      acc[0][2] = __builtin_amdgcn_mfma_scale_f32_16x16x128_f8f6f4(a0.v, u2.v, acc[0][2], 0, 0, 0, SC1, 0, SC1);
      acc[0][3] = __builtin_amdgcn_mfma_scale_f32_16x16x128_f8f6f4(a0.v, u3.v, acc[0][3], 0, 0, 0, SC1, 0, SC1);
      acc[1][2] = __builtin_amdgcn_mfma_scale_f32_16x16x128_f8f6f4(a1.v, u2.v, acc[1][2], 0, 0, 0, SC1, 0, SC1);
      acc[1][3] = __builtin_amdgcn_mfma_scale_f32_16x16x128_f8f6f4(a1.v, u3.v, acc[1][3], 0, 0, 0, SC1, 0, SC1);
    }
    // build rows jA, jB (VALU issues in MFMA shadow)
    {
      float r0 = rA.x, r1 = rA.y;
      float h0 = fmaxf(fmaf(r1, wt1[0], fmaf(r0, wt0[0], xA[0])), 0.f);
      float h1 = fmaxf(fmaf(r1, wt1[1], fmaf(r0, wt0[1], xA[1])), 0.f);
      float h2 = fmaxf(fmaf(r1, wt1[2], fmaf(r0, wt0[2], xA[2])), 0.f);
      float h3 = fmaxf(fmaf(r1, wt1[3], fmaf(r0, wt0[3], xA[3])), 0.f);
      int d = __builtin_amdgcn_cvt_pk_fp8_f32(h0, h1, 0, false);
      d     = __builtin_amdgcn_cvt_pk_fp8_f32(h2, h3, d, true);
      *reinterpret_cast<int*>(lA8 + jA * LDA8 + c0) = d;
    }
    {
      float r0 = rB.x, r1 = rB.y;
      float h0 = fmaxf(fmaf(r1, wt1[0], fmaf(r0, wt0[0], xB[0])), 0.f);
      float h1 = fmaxf(fmaf(r1, wt1[1], fmaf(r0, wt0[1], xB[1])), 0.f);
      float h2 = fmaxf(fmaf(r1, wt1[2], fmaf(r0, wt0[2], xB[2])), 0.f);
      float h3 = fmaxf(fmaf(r1, wt1[3], fmaf(r0, wt0[3], xB[3])), 0.f);
      int d = __builtin_amdgcn_cvt_pk_fp8_f32(h0, h1, 0, false);
      d     = __builtin_amdgcn_cvt_pk_fp8_f32(h2, h3, d, true);
      *reinterpret_cast<int*>(lA8 + jB * LDA8 + c0) = d;
    }
  }
  __syncthreads();

  float bbf[4];
#pragma unroll
  for(int nt = 0; nt < 4; ++nt) bbf[nt] = bimp[w * 64 + nt * 16 + ln] * -LOG2E;

  // ---- section B: K for mt2/3 + mt0/1 sigmoid+rowsum interleaved ----
#pragma unroll 1
  for(int sI = 0; sI < 4; ++sI){
    const int s128 = (st + sI) & 3;
    const unsigned char* Bb = Wsw8 + (size_t)(s128 * 32 + w * 4) * 2048 + (size_t)lane * 16;
    U8 a2, a3;
    const unsigned char* ap2 = lA8 + (32 + ln) * LDA8 + s128 * 128 + quad * 32;
    const unsigned char* ap3 = ap2 + 16 * LDA8;
    a2.q[0] = *reinterpret_cast<const uint4*>(ap2);
    a2.q[1] = *reinterpret_cast<const uint4*>(ap2 + 16);
    a3.q[0] = *reinterpret_cast<const uint4*>(ap3);
    a3.q[1] = *reinterpret_cast<const uint4*>(ap3 + 16);
    {
      U8 u0, u1;
      u0.q[0] = *reinterpret_cast<const uint4*>(Bb);
      u0.q[1] = *reinterpret_cast<const uint4*>(Bb + 1024);
      u1.q[0] = *reinterpret_cast<const uint4*>(Bb + 2048);
      u1.q[1] = *reinterpret_cast<const uint4*>(Bb + 3072);
      acc[2][0] = __builtin_amdgcn_mfma_scale_f32_16x16x128_f8f6f4(a2.v, u0.v, acc[2][0], 0, 0, 0, SC1, 0, SC1);
      acc[2][1] = __builtin_amdgcn_mfma_scale_f32_16x16x128_f8f6f4(a2.v, u1.v, acc[2][1], 0, 0, 0, SC1, 0, SC1);
      acc[3][0] = __builtin_amdgcn_mfma_scale_f32_16x16x128_f8f6f4(a3.v, u0.v, acc[3][0], 0, 0, 0, SC1, 0, SC1);
      acc[3][1] = __builtin_amdgcn_mfma_scale_f32_16x16x128_f8f6f4(a3.v, u1.v, acc[3][1], 0, 0, 0, SC1, 0, SC1);
    }
    {
      U8 u2, u3;
      u2.q[0] = *reinterpret_cast<const uint4*>(Bb + 4096);
      u2.q[1] = *reinterpret_cast<const uint4*>(Bb + 5120);
      u3.q[0] = *reinterpret_cast<const uint4*>(Bb + 6144);
      u3.q[1] = *reinterpret_cast<const uint4*>(Bb + 7168);
      acc[2][2] = __builtin_amdgcn_mfma_scale_f32_16x16x128_f8f6f4(a2.v, u2.v, acc[2][2], 0, 0, 0, SC1, 0, SC1);
      acc[2][3] = __builtin_amdgcn_mfma_scale_f32_16x16x128_f8f6f4(a2.v, u3.v, acc[2][3], 0, 0, 0, SC1, 0, SC1);
      acc[3][2] = __builtin_amdgcn_mfma_scale_f32_16x16x128_f8f6f4(a3.v, u2.v, acc[3][2], 0, 0, 0, SC1, 0, SC1);
      acc[3][3] = __builtin_amdgcn_mfma_scale_f32_16x16x128_f8f6f4(a3.v, u3.v, acc[3][3], 0, 0, 0, SC1, 0, SC1);
    }
    // mt0/1 sigmoid chunks p = 2sI, 2sI+1 (trans in MFMA shadow)
#pragma unroll
    for(int h = 0; h < 2; ++h){
      const int p = sI * 2 + h;
      const int mt = p >> 2, r = p & 3;
      float mk = msk[mt * 16 + quad * 4 + r];
      float pp = 0.f;
#pragma unroll
      for(int nt = 0; nt < 4; ++nt){
        float zn = fmaf(acc[mt][nt][r], NZL, bbf[nt]);
        float im = mk * __builtin_amdgcn_rcpf(1.f + __builtin_amdgcn_exp2f(zn));
        acc[mt][nt][r] = im;
        pp += im;
      }
      pp += __shfl_xor(pp, 1, 64);
      pp += __shfl_xor(pp, 2, 64);
      pp += __shfl_xor(pp, 4, 64);
      pp += __shfl_xor(pp, 8, 64);
      if(ln == 0) atomicAdd(&rsum[mt * 16 + quad * 4 + r], pp);
    }
  }

  // mt2/3 sigmoid chunks
#pragma unroll
  for(int p = 8; p < 16; ++p){
    const int mt = p >> 2, r = p & 3;
    float mk = msk[mt * 16 + quad * 4 + r];
    float pp = 0.f;
#pragma unroll
    for(int nt = 0; nt < 4; ++nt){
      float zn = fmaf(acc[mt][nt][r], NZL, bbf[nt]);
      float im = mk * __builtin_amdgcn_rcpf(1.f + __builtin_amdgcn_exp2f(zn));
      acc[mt][nt][r] = im;
      pp += im;
    }
    pp += __shfl_xor(pp, 1, 64);
    pp += __shfl_xor(pp, 2, 64);
    pp += __shfl_xor(pp, 4, 64);
    pp += __shfl_xor(pp, 8, 64);
    if(ln == 0) atomicAdd(&rsum[mt * 16 + quad * 4 + r], pp);
  }

  // values (bf16 *log2e, frag order) + x for out0
  uint4 vv[8];
#pragma unroll
  for(int eb = 0; eb < 8; ++eb)
    vv[eb] = *reinterpret_cast<const uint4*>(vfrag + ((size_t)((b * 8 + w) * 8 + eb) * 64 + lane) * 8);
  float xq[4];
#pragma unroll
  for(int nt = 0; nt < 4; ++nt)
    xq[nt] = x[(size_t)bi * Cn + (w * 64 + nt * 16 + ln)];

  // se pass (order mt,r,nt — matches prior rounds bit-exactly)
  const unsigned int* vw = reinterpret_cast<const unsigned int*>(vv);
  float se[4] = {0.f, 0.f, 0.f, 0.f};
#pragma unroll
  for(int mt = 0; mt < 4; ++mt)
#pragma unroll
    for(int r = 0; r < 4; ++r)
#pragma unroll
      for(int nt = 0; nt < 4; ++nt){
        int e = mt * 16 + nt * 4 + r;
        unsigned int d = vw[e >> 1];
        float vl = bits2f((e & 1) ? (d & 0xffff0000u) : (d << 16));
        se[nt] += __builtin_amdgcn_exp2f(vl * acc[mt][nt][r]);
      }
  __syncthreads();
  if(tid < Tn) out1[(size_t)bi * Tn + tid] = rsum[tid] * (1.f / 512.f);

#pragma unroll
  for(int nt = 0; nt < 4; ++nt){
    float s0 = se[nt];
    s0 += __shfl_xor(s0, 16, 64);
    s0 += __shfl_xor(s0, 32, 64);
    if(quad == 0){
      int idx = bi * Cn + (w * 64 + nt * 16 + ln);
      out0[idx] = xq[nt] + __builtin_amdgcn_logf(s0) * LN2;
    }
  }
}

extern "C" void kernel_launch(void* const* d_in, const int* in_sizes, int n_in,
                              void* d_out, int out_size, void* d_ws, size_t ws_size,
                              hipStream_t stream){
  const float* x    = (const float*)d_in[0];
  const float* ts   = (const float*)d_in[1];
  const float* am   = (const float*)d_in[2];
  const float* Wp   = (const float*)d_in[3];
  const float* bp   = (const float*)d_in[4];
  const float* Wx   = (const float*)d_in[5];
  const float* bx   = (const float*)d_in[6];
  const float* Wt   = (const float*)d_in[7];
  const float* bt   = (const float*)d_in[8];
  const float* Wi   = (const float*)d_in[9];
  const float* bimp = (const float*)d_in[10];
  float* out0 = (float*)d_out;
  float* out1 = out0 + Bn * Tn * Cn;

  char* ws = (char*)d_ws;
  unsigned char*  Wsw8  = (unsigned char*)ws;                   // 256KB: Wi fp8 K=128 frags
  float*          xe    = (float*)(ws + 262144);                // 2MB f32 (scaled x16)
  unsigned short* vfrag = (unsigned short*)(ws + 2359296);      // 1MB bf16 frag-order
  float*          R     = (float*)(ws + 3407872);               // 512KB log1p table

  pre<<<192, 512, 0, stream>>>(x, ts, Wp, bp, Wx, bx, bt, Wi, xe, vfrag, Wsw8, R);
  fused<<<1024, 512, 0, stream>>>(x, am, Wt, bimp, Wsw8, R, xe, vfrag, out0, out1);
}

// Round 10
// 118.554 us; speedup vs baseline: 2.1555x; 2.1555x over previous
//
#include <hip/hip_runtime.h>
#include <hip/hip_bf16.h>

#define Bn 16
#define Tn 64
#define Cn 512
#define LDA  520    // bf16 row stride in shorts (pre A tile)
#define LDA8 528    // fp8 row stride in bytes (fused A tile)

#define LOG2E 1.4426950408889634f
#define LN2   0.6931471805599453f
#define ASC 16.0f          // A (relu h) scale, folded into xe / Wt
#define WSC 256.0f         // W_imp scale (lifts out of e4m3 subnormals)
#define ZSC (1.0f/4096.0f) // 1/(ASC*WSC) unscale
#define NZL (-(LOG2E)*(ZSC)) // folded -log2e/4096 for sigmoid arg
#define SC1 0x7F7F7F7FU    // E8M0 unit scales (127 -> 2^0)

typedef short s8v __attribute__((ext_vector_type(8)));          // 8 bf16 frag
typedef float f4v __attribute__((ext_vector_type(4)));          // MFMA acc
typedef int   i8v __attribute__((ext_vector_type(8)));          // 32B fp8 frag (K=128)

__device__ __forceinline__ unsigned int pk2bf(float a, float b){
  __hip_bfloat162 t = __float22bfloat162_rn(make_float2(a, b));
  union { __hip_bfloat162 h; unsigned int u; } c; c.h = t; return c.u;
}
__device__ __forceinline__ float bits2f(unsigned int u){
  union { unsigned int u; float f; } c; c.u = u; return c.f;
}
__device__ __forceinline__ s8v pack_bf8(const float* v){
  union { uint4 u; s8v s; } c;
  c.u.x = pk2bf(v[0], v[1]); c.u.y = pk2bf(v[2], v[3]);
  c.u.z = pk2bf(v[4], v[5]); c.u.w = pk2bf(v[6], v[7]);
  return c.s;
}
union U8 { uint4 q[2]; i8v v; };

// ---------------------------------------------------------------------------
// pre: 192 blocks x 512 thr (single CU generation).
//  [0,32):   R table log1p(max(+/-(ts_i-ts_j),0)) -> R
//  [32,64):  Wi f32 *256 -> fp8 e4m3 K=128 frag planes (round-7 layout)
//  [64,192): GEMM blocks (b, mat, half): 8 waves, wave = 1 n-tile t=half*8+w.
//     mat=0: values=x@Wp+bp -> vfrag bf16 *log2e (fused C-frag order)
//     mat=1: xe=(x@Wx+bx+bt)*ASC (f32 row-major)
// ---------------------------------------------------------------------------
__global__ __launch_bounds__(512)
void pre(const float* __restrict__ x, const float* __restrict__ ts,
         const float* __restrict__ Wp, const float* __restrict__ bp,
         const float* __restrict__ Wx, const float* __restrict__ bx,
         const float* __restrict__ bt, const float* __restrict__ Wi,
         float* __restrict__ xe, unsigned short* __restrict__ vfrag,
         unsigned char* __restrict__ Wsw8, float* __restrict__ R){
  __shared__ unsigned short lA[Tn * LDA];
  const int blk = blockIdx.x;
  const int tid = threadIdx.x;
  if(blk < 32){
    int gid2 = blk * 512 + tid;                      // 16384 threads, 4 pairs each
    float r[8];
#pragma unroll
    for(int q = 0; q < 4; ++q){
      int p = gid2 * 4 + q;
      int b = p >> 12, i = (p >> 6) & 63, j = p & 63;
      float d = ts[b * Tn + i] - ts[b * Tn + j];
      r[2*q]   = __logf(1.f + fmaxf(d, 0.f));
      r[2*q+1] = __logf(1.f + fmaxf(-d, 0.f));
    }
    float4* Rf4 = reinterpret_cast<float4*>(R);
    Rf4[gid2 * 2    ] = make_float4(r[0], r[1], r[2], r[3]);
    Rf4[gid2 * 2 + 1] = make_float4(r[4], r[5], r[6], r[7]);
    return;
  }
  if(blk < 64){
    int rem = (blk - 32) * 512 + tid;                // 16384 threads, 16B each
    int p    = rem & 1;
    int lane = (rem >> 1) & 63;
    int t    = (rem >> 7) & 31;
    int s128 = rem >> 12;
    int quad = lane >> 4, ln = lane & 15;
    int k0 = s128 * 128 + quad * 32 + p * 16;
    int n  = t * 16 + ln;
    float v[16];
#pragma unroll
    for(int j = 0; j < 16; ++j) v[j] = Wi[(k0 + j) * Cn + n] * WSC;
    unsigned int d[4];
#pragma unroll
    for(int g = 0; g < 4; ++g){
      int dd = __builtin_amdgcn_cvt_pk_fp8_f32(v[4*g],   v[4*g+1], 0, false);
      dd     = __builtin_amdgcn_cvt_pk_fp8_f32(v[4*g+2], v[4*g+3], dd, true);
      d[g] = (unsigned int)dd;
    }
    uint4 o; o.x = d[0]; o.y = d[1]; o.z = d[2]; o.w = d[3];
    *reinterpret_cast<uint4*>(Wsw8 + (size_t)(s128 * 32 + t) * 2048 + p * 1024 + lane * 16) = o;
    return;
  }
  // ---- GEMM blocks ----
  const int idx = blk - 64;
  const int b = idx >> 3, mat = (idx >> 2) & 1, half = idx & 3;
  const int lane = tid & 63, w = tid >> 6, quad = lane >> 4, ln = lane & 15;
  const int t = half * 8 + w;                        // n-tile 0..31
  const float* Wg = mat ? Wx : Wp;
  const float* wb = Wg + (size_t)(quad * 8) * Cn + t * 16 + ln;

  const int c0 = (tid & 127) * 4, jb = tid >> 7;     // jb in {0..3}
#pragma unroll
  for(int it = 0; it < 16; ++it){
    int j = jb + it * 4;
    f4v xv = *reinterpret_cast<const f4v*>(x + ((b * Tn + j) * Cn + c0));
    uint2 uu; uu.x = pk2bf(xv[0], xv[1]); uu.y = pk2bf(xv[2], xv[3]);
    *reinterpret_cast<uint2*>(&lA[j * LDA + c0]) = uu;
  }
  float wv[8];
#pragma unroll
  for(int j = 0; j < 8; ++j) wv[j] = wb[j * Cn];
  __syncthreads();

  s8v a[4], an[4];
#pragma unroll
  for(int mt = 0; mt < 4; ++mt)
    a[mt] = *reinterpret_cast<const s8v*>(&lA[(mt * 16 + ln) * LDA + quad * 8]);
  f4v acc[4];
#pragma unroll
  for(int mt = 0; mt < 4; ++mt){ acc[mt][0]=0.f; acc[mt][1]=0.f; acc[mt][2]=0.f; acc[mt][3]=0.f; }
  s8v bcur = pack_bf8(wv);

#pragma unroll 2
  for(int s = 0; s < 16; ++s){
    int sn = (s + 1) & 15;
    float wn[8];
#pragma unroll
    for(int j = 0; j < 8; ++j) wn[j] = wb[(size_t)sn * 32 * Cn + j * Cn];
#pragma unroll
    for(int mt = 0; mt < 4; ++mt)
      an[mt] = *reinterpret_cast<const s8v*>(&lA[(mt * 16 + ln) * LDA + sn * 32 + quad * 8]);
#pragma unroll
    for(int mt = 0; mt < 4; ++mt)
      acc[mt] = __builtin_amdgcn_mfma_f32_16x16x32_bf16(a[mt], bcur, acc[mt], 0, 0, 0);
#pragma unroll
    for(int mt = 0; mt < 4; ++mt) a[mt] = an[mt];
    bcur = pack_bf8(wn);
  }

  const int c = t * 16 + ln;
  const int oct = t >> 2, w2 = t & 3;
  if(mat == 0){
    float bb = bp[c];
    const int eb_h = w2 & 1;
#pragma unroll
    for(int mt = 0; mt < 4; ++mt){
      float v0 = (acc[mt][0] + bb) * LOG2E;
      float v1 = (acc[mt][1] + bb) * LOG2E;
      float v2 = (acc[mt][2] + bb) * LOG2E;
      float v3 = (acc[mt][3] + bb) * LOG2E;
      uint2 o; o.x = pk2bf(v0, v1); o.y = pk2bf(v2, v3);
      int eb = mt * 2 + (w2 >> 1);
      *reinterpret_cast<uint2*>(vfrag + ((size_t)((b * 8 + oct) * 8 + eb) * 64 + lane) * 8 + eb_h * 4) = o;
    }
  } else {
    float bb = bx[c] + bt[c];
#pragma unroll
    for(int mt = 0; mt < 4; ++mt)
#pragma unroll
      for(int r = 0; r < 4; ++r){
        int j = mt * 16 + quad * 4 + r;
        xe[(b * Tn + j) * Cn + c] = (acc[mt][r] + bb) * ASC;
      }
  }
}

// ---------------------------------------------------------------------------
// fused (round-8 proven version, byte-identical): one 512-thr block per (b,i).
// MX K=128 arithmetic, spill-proof: B loaded inside each step, used directly;
// #pragma unroll 1 K-loop so the compiler can't pipeline loads across steps.
// Live peak ~114 VGPR < 128 cap. Merged sigmoid+LSE epilogue.
// ---------------------------------------------------------------------------
__global__ __launch_bounds__(512, 4)
void fused(const float* __restrict__ x, const float* __restrict__ am,
           const float* __restrict__ Wt, const float* __restrict__ bimp,
           const unsigned char* __restrict__ Wsw8, const float* __restrict__ R,
           const float* __restrict__ xe, const unsigned short* __restrict__ vfrag,
           float* __restrict__ out0, float* __restrict__ out1){
  __shared__ unsigned char lA8[Tn * LDA8];
  __shared__ float msk[Tn], rr0[Tn], rr1[Tn], rsum[Tn];
  const int b = blockIdx.x >> 6, i = blockIdx.x & 63;
  const int tid = threadIdx.x;
  const int lane = tid & 63, w = tid >> 6, quad = lane >> 4, ln = lane & 15;
  const int st = blockIdx.x & 3;                     // K start phase 0..3

  // small staging loads first
  float mv = 0.f; float2 rv = make_float2(0.f, 0.f);
  if(tid < Tn){
    mv = am[b * Tn + tid];
    rv = reinterpret_cast<const float2*>(R)[(b * Tn + i) * Tn + tid];
  }

  // hoisted xe loads: in flight across the staging barrier
  const int c0 = (tid & 127) * 4, jb = tid >> 7;
  f4v xv[16];
#pragma unroll
  for(int it = 0; it < 16; ++it)
    xv[it] = *reinterpret_cast<const f4v*>(xe + ((b * Tn + (jb + it * 4)) * Cn + c0));

  if(tid < Tn){ msk[tid] = mv; rr0[tid] = rv.x; rr1[tid] = rv.y; rsum[tid] = 0.f; }
  __syncthreads();

  f4v wt0 = *reinterpret_cast<const f4v*>(Wt + c0);
  f4v wt1 = *reinterpret_cast<const f4v*>(Wt + Cn + c0);
  wt0[0]*=ASC; wt0[1]*=ASC; wt0[2]*=ASC; wt0[3]*=ASC;   // xe already x16
  wt1[0]*=ASC; wt1[1]*=ASC; wt1[2]*=ASC; wt1[3]*=ASC;
#pragma unroll
  for(int it = 0; it < 16; ++it){
    int j = jb + it * 4;
    float r0 = rr0[j], r1 = rr1[j];
    float h0 = fmaxf(fmaf(r1, wt1[0], fmaf(r0, wt0[0], xv[it][0])), 0.f);
    float h1 = fmaxf(fmaf(r1, wt1[1], fmaf(r0, wt0[1], xv[it][1])), 0.f);
    float h2 = fmaxf(fmaf(r1, wt1[2], fmaf(r0, wt0[2], xv[it][2])), 0.f);
    float h3 = fmaxf(fmaf(r1, wt1[3], fmaf(r0, wt0[3], xv[it][3])), 0.f);
    int d = __builtin_amdgcn_cvt_pk_fp8_f32(h0, h1, 0, false);
    d     = __builtin_amdgcn_cvt_pk_fp8_f32(h2, h3, d, true);
    *reinterpret_cast<int*>(lA8 + j * LDA8 + c0) = d;
  }
  __syncthreads();

  f4v acc[4][4];
#pragma unroll
  for(int mt = 0; mt < 4; ++mt)
#pragma unroll
    for(int nt = 0; nt < 4; ++nt){
      acc[mt][nt][0]=0.f; acc[mt][nt][1]=0.f; acc[mt][nt][2]=0.f; acc[mt][nt][3]=0.f;
    }

#pragma unroll 1
  for(int sI = 0; sI < 4; ++sI){
    const int s128 = (st + sI) & 3;
    // B loads for this step only (32 transient VGPRs, no cross-step pipeline)
    U8 ub0, ub1, ub2, ub3;
    const unsigned char* Bb = Wsw8 + (size_t)(s128 * 32 + w * 4) * 2048 + lane * 16;
    ub0.q[0] = *reinterpret_cast<const uint4*>(Bb);
    ub0.q[1] = *reinterpret_cast<const uint4*>(Bb + 1024);
    ub1.q[0] = *reinterpret_cast<const uint4*>(Bb + 2048);
    ub1.q[1] = *reinterpret_cast<const uint4*>(Bb + 3072);
    ub2.q[0] = *reinterpret_cast<const uint4*>(Bb + 4096);
    ub2.q[1] = *reinterpret_cast<const uint4*>(Bb + 5120);
    ub3.q[0] = *reinterpret_cast<const uint4*>(Bb + 6144);
    ub3.q[1] = *reinterpret_cast<const uint4*>(Bb + 7168);
#pragma unroll
    for(int mt = 0; mt < 4; ++mt){
      U8 ua;
      const unsigned char* ap = lA8 + (mt * 16 + ln) * LDA8 + s128 * 128 + quad * 32;
      ua.q[0] = *reinterpret_cast<const uint4*>(ap);
      ua.q[1] = *reinterpret_cast<const uint4*>(ap + 16);
      acc[mt][0] = __builtin_amdgcn_mfma_scale_f32_16x16x128_f8f6f4(ua.v, ub0.v, acc[mt][0], 0, 0, 0, SC1, 0, SC1);
      acc[mt][1] = __builtin_amdgcn_mfma_scale_f32_16x16x128_f8f6f4(ua.v, ub1.v, acc[mt][1], 0, 0, 0, SC1, 0, SC1);
      acc[mt][2] = __builtin_amdgcn_mfma_scale_f32_16x16x128_f8f6f4(ua.v, ub2.v, acc[mt][2], 0, 0, 0, SC1, 0, SC1);
      acc[mt][3] = __builtin_amdgcn_mfma_scale_f32_16x16x128_f8f6f4(ua.v, ub3.v, acc[mt][3], 0, 0, 0, SC1, 0, SC1);
    }
  }

  // values (bf16, pre-scaled by log2e), frag order: 8 coalesced 16B loads
  uint4 vv[8];
#pragma unroll
  for(int eb = 0; eb < 8; ++eb)
    vv[eb] = *reinterpret_cast<const uint4*>(vfrag + ((size_t)((b * 8 + w) * 8 + eb) * 64 + lane) * 8);
  // x for the out0 epilogue — hoisted so latency hides under the trans loop
  float xq[4];
#pragma unroll
  for(int nt = 0; nt < 4; ++nt)
    xq[nt] = x[(b * Tn + i) * Cn + (w * 64 + nt * 16 + ln)];

  // merged epilogue: sigmoid (folded -log2e/4096 + bias) + out1 rowsum + LSE
  const unsigned int* vw = reinterpret_cast<const unsigned int*>(vv);
  float bbf[4];
#pragma unroll
  for(int nt = 0; nt < 4; ++nt) bbf[nt] = bimp[w * 64 + nt * 16 + ln] * -LOG2E;
  float se[4] = {0.f, 0.f, 0.f, 0.f};
#pragma unroll
  for(int mt = 0; mt < 4; ++mt)
#pragma unroll
    for(int r = 0; r < 4; ++r){
      float mk = msk[mt * 16 + quad * 4 + r];
      float p = 0.f;
#pragma unroll
      for(int nt = 0; nt < 4; ++nt){
        float zn = fmaf(acc[mt][nt][r], NZL, bbf[nt]);   // = -log2e * z
        float im = mk * __builtin_amdgcn_rcpf(1.f + __builtin_amdgcn_exp2f(zn));
        p += im;
        int e = mt * 16 + nt * 4 + r;
        unsigned int d = vw[e >> 1];
        float vl = bits2f((e & 1) ? (d & 0xffff0000u) : (d << 16));
        se[nt] += __builtin_amdgcn_exp2f(vl * im);
      }
      p += __shfl_xor(p, 1, 64);
      p += __shfl_xor(p, 2, 64);
      p += __shfl_xor(p, 4, 64);
      p += __shfl_xor(p, 8, 64);
      if(ln == 0) atomicAdd(&rsum[mt * 16 + quad * 4 + r], p);
    }
  __syncthreads();
  if(tid < Tn) out1[(b * Tn + i) * Tn + tid] = rsum[tid] * (1.f / 512.f);

#pragma unroll
  for(int nt = 0; nt < 4; ++nt){
    float s0 = se[nt];
    s0 += __shfl_xor(s0, 16, 64);
    s0 += __shfl_xor(s0, 32, 64);
    if(quad == 0){
      int idx = (b * Tn + i) * Cn + (w * 64 + nt * 16 + ln);
      out0[idx] = xq[nt] + __builtin_amdgcn_logf(s0) * LN2;
    }
  }
}

extern "C" void kernel_launch(void* const* d_in, const int* in_sizes, int n_in,
                              void* d_out, int out_size, void* d_ws, size_t ws_size,
                              hipStream_t stream){
  const float* x    = (const float*)d_in[0];
  const float* ts   = (const float*)d_in[1];
  const float* am   = (const float*)d_in[2];
  const float* Wp   = (const float*)d_in[3];
  const float* bp   = (const float*)d_in[4];
  const float* Wx   = (const float*)d_in[5];
  const float* bx   = (const float*)d_in[6];
  const float* Wt   = (const float*)d_in[7];
  const float* bt   = (const float*)d_in[8];
  const float* Wi   = (const float*)d_in[9];
  const float* bimp = (const float*)d_in[10];
  float* out0 = (float*)d_out;
  float* out1 = out0 + Bn * Tn * Cn;

  char* ws = (char*)d_ws;
  unsigned char*  Wsw8  = (unsigned char*)ws;                   // 256KB: Wi fp8 K=128 frags
  float*          xe    = (float*)(ws + 262144);                // 2MB f32 (scaled x16)
  unsigned short* vfrag = (unsigned short*)(ws + 2359296);      // 1MB bf16 frag-order
  float*          R     = (float*)(ws + 3407872);               // 512KB log1p table

  pre<<<192, 512, 0, stream>>>(x, ts, Wp, bp, Wx, bx, bt, Wi, xe, vfrag, Wsw8, R);
  fused<<<1024, 512, 0, stream>>>(x, am, Wt, bimp, Wsw8, R, xe, vfrag, out0, out1);
}